// Round 4
// baseline (167.472 us; speedup 1.0000x reference)
//
#include <hip/hip_runtime.h>
#include <hip/hip_fp16.h>
#include <math.h>

#define B_ 4
#define K_ 4
#define D_ 96
#define L_ 2048
#define N_ 16
#define R_ 6
#define C_ 38          // R + 2N

__device__ __forceinline__ float softplus_f(float x) {
    return fmaxf(x, 0.f) + __logf(1.f + __expf(-fabsf(x)));
}

// BC layout (fp16, chunk-interleaved for wave-coalesced scan reads):
//   uint4 (=8 halfs) at index (((bk*8 + i)*4 + j)*256 + t), where l = t*8+i
//   j=0: B n0..7   j=1: B n8..15   j=2: C n0..7   j=3: C n8..15
// At scan step i, lane t reads 16B at 16B lane stride -> perfect coalescing.

// ---------------------------------------------------------------------------
// Proj: grid (B*K, 4, 6), block 256, thread covers l0 and l0+256.
//   cg 0,1 -> B n-octet cg ; cg 2,3 -> C n-octet cg-2 ; cg 4 -> dts r0..3 ;
//   cg 5 -> dts r4..5
// ---------------------------------------------------------------------------
__global__ __launch_bounds__(256) void proj_kernel(
    const float* __restrict__ xs, const float* __restrict__ xpw,
    uint4* __restrict__ BCc, float* __restrict__ dts_ws)
{
    __shared__ float sW[8 * D_];
    const int bk = blockIdx.x;
    const int k = bk & 3;
    const int cg = blockIdx.z;
    const int tid = threadIdx.x;

    int c0, nrows;
    if (cg < 2)       { c0 = R_ + cg * 8;            nrows = 8; }
    else if (cg < 4)  { c0 = R_ + 16 + (cg - 2) * 8; nrows = 8; }
    else if (cg == 4) { c0 = 0;                      nrows = 4; }
    else              { c0 = 4;                      nrows = 2; }

    for (int i = tid; i < 8 * D_; i += 256) {
        if (i < nrows * D_) sW[i] = xpw[(k * C_ + c0 + i / D_) * D_ + (i % D_)];
        else sW[i] = 0.f;
    }
    __syncthreads();

    const int l0 = blockIdx.y * 512 + tid;
    const float* X = xs + (size_t)bk * D_ * L_;

    float acc[8][2];
#pragma unroll
    for (int r = 0; r < 8; ++r) { acc[r][0] = 0.f; acc[r][1] = 0.f; }

#pragma unroll 4
    for (int d = 0; d < D_; ++d) {
        const float x0 = X[d * L_ + l0];
        const float x1 = X[d * L_ + l0 + 256];
#pragma unroll
        for (int r = 0; r < 8; ++r) {
            const float w = sW[r * D_ + d];
            acc[r][0] = fmaf(w, x0, acc[r][0]);
            acc[r][1] = fmaf(w, x1, acc[r][1]);
        }
    }

    if (cg < 4) {
        const int j = cg;
#pragma unroll
        for (int jj = 0; jj < 2; ++jj) {
            const int l = l0 + jj * 256;
            const int i = l & 7, t = l >> 3;
            union { __half h[8]; uint4 v; } p;
#pragma unroll
            for (int e = 0; e < 8; ++e) p.h[e] = __float2half(acc[e][jj]);
            BCc[(((size_t)bk * 8 + i) * 4 + j) * 256 + t] = p.v;
        }
    } else {
        const int rbase = (cg == 4) ? 0 : 4;
        const int rcnt = (cg == 4) ? 4 : 2;
        for (int r = 0; r < rcnt; ++r)
#pragma unroll
            for (int jj = 0; jj < 2; ++jj)
                dts_ws[((size_t)bk * R_ + rbase + r) * L_ + l0 + jj * 256] = acc[r][jj];
    }
}

// ---------------------------------------------------------------------------
// Scan: grid B*K*D, block 256; thread owns l in [tid*8, tid*8+8).
// fp16 B/C, 2-deep software-pipelined loads, phase-3 prefetch hidden
// under the shuffle-scan tree.
// ---------------------------------------------------------------------------
__global__ __launch_bounds__(256) void scan_kernel(
    const float* __restrict__ xs, const float* __restrict__ A_logs,
    const float* __restrict__ Ds, const float* __restrict__ dtw,
    const float* __restrict__ dtb, const float* __restrict__ dts_ws,
    const uint4* __restrict__ BCc, float* __restrict__ out)
{
    __shared__ float sAw[4][N_];
    __shared__ float sBw[4][N_];

    const int bkd = blockIdx.x;
    const int d = bkd % D_;
    const int bk = bkd / D_;
    const int k = bk & 3;
    const int kd = k * D_ + d;
    const int tid = threadIdx.x;
    const int lane = tid & 63;
    const int wave = tid >> 6;

    const uint4* BC = BCc + (size_t)bk * 8 * 4 * 256;

    // xs chunk -> registers
    const float4* xv4 = (const float4*)(xs + (size_t)bkd * L_);
    const float4 xa = xv4[tid * 2], xb = xv4[tid * 2 + 1];
    float x[8] = {xa.x, xa.y, xa.z, xa.w, xb.x, xb.y, xb.z, xb.w};

    // delta chunk
    float del[8];
    const float bias = dtb[kd];
#pragma unroll
    for (int j = 0; j < 8; ++j) del[j] = bias;
    const float* w2 = dtw + (size_t)kd * R_;
    const float4* dts4 = (const float4*)(dts_ws + (size_t)bk * R_ * L_);
#pragma unroll
    for (int r = 0; r < R_; ++r) {
        const float wr = w2[r];
        const float4 t0 = dts4[r * (L_ / 4) + tid * 2];
        const float4 t1 = dts4[r * (L_ / 4) + tid * 2 + 1];
        del[0] = fmaf(wr, t0.x, del[0]); del[1] = fmaf(wr, t0.y, del[1]);
        del[2] = fmaf(wr, t0.z, del[2]); del[3] = fmaf(wr, t0.w, del[3]);
        del[4] = fmaf(wr, t1.x, del[4]); del[5] = fmaf(wr, t1.y, del[5]);
        del[6] = fmaf(wr, t1.z, del[6]); del[7] = fmaf(wr, t1.w, del[7]);
    }
#pragma unroll
    for (int j = 0; j < 8; ++j) del[j] = softplus_f(del[j]);

    float A[N_];
    const float* Ap = A_logs + (size_t)kd * N_;
#pragma unroll
    for (int n = 0; n < N_; ++n) A[n] = -__expf(Ap[n]);
    const float Dval = Ds[kd];

    // Phase 1: per-chunk aggregate, 2-deep pipelined B loads (2/step)
    uint4 pb[2][2];
    pb[0][0] = BC[(0 * 4 + 0) * 256 + tid];
    pb[0][1] = BC[(0 * 4 + 1) * 256 + tid];
    pb[1][0] = BC[(1 * 4 + 0) * 256 + tid];
    pb[1][1] = BC[(1 * 4 + 1) * 256 + tid];

    float a[N_], b[N_];
#pragma unroll
    for (int n = 0; n < N_; ++n) { a[n] = 1.f; b[n] = 0.f; }
#pragma unroll
    for (int i = 0; i < 8; ++i) {
        const uint4 c0 = pb[i & 1][0], c1 = pb[i & 1][1];
        if (i < 6) {
            pb[i & 1][0] = BC[((i + 2) * 4 + 0) * 256 + tid];
            pb[i & 1][1] = BC[((i + 2) * 4 + 1) * 256 + tid];
        }
        const __half* h0 = (const __half*)&c0;
        const __half* h1 = (const __half*)&c1;
        float Bl[N_];
#pragma unroll
        for (int e = 0; e < 8; ++e) {
            Bl[e] = __half2float(h0[e]);
            Bl[8 + e] = __half2float(h1[e]);
        }
        const float dl = del[i];
        const float dx = dl * x[i];
#pragma unroll
        for (int n = 0; n < N_; ++n) {
            const float dA = __expf(dl * A[n]);
            b[n] = fmaf(dA, b[n], dx * Bl[n]);
            a[n] *= dA;
        }
    }

    // Prefetch phase-3 steps 0,1 (B+C) -- latency hidden under shuffle scan
    uint4 qb[2][4];
#pragma unroll
    for (int j = 0; j < 4; ++j) {
        qb[0][j] = BC[(0 * 4 + j) * 256 + tid];
        qb[1][j] = BC[(1 * 4 + j) * 256 + tid];
    }

    // Phase 2a: wave-level inclusive scan
#pragma unroll
    for (int off = 1; off < 64; off <<= 1) {
#pragma unroll
        for (int n = 0; n < N_; ++n) {
            const float pa = __shfl_up(a[n], off, 64);
            const float pb2 = __shfl_up(b[n], off, 64);
            if (lane >= off) {
                b[n] = fmaf(a[n], pb2, b[n]);
                a[n] *= pa;
            }
        }
    }
    // Phase 2b: cross-wave fixup
    if (lane == 63) {
#pragma unroll
        for (int n = 0; n < N_; ++n) { sAw[wave][n] = a[n]; sBw[wave][n] = b[n]; }
    }
    __syncthreads();

    // h at chunk start
    float h[N_];
#pragma unroll
    for (int n = 0; n < N_; ++n) {
        float ae = __shfl_up(a[n], 1, 64);
        float be = __shfl_up(b[n], 1, 64);
        if (lane == 0) { ae = 1.f; be = 0.f; }
        float wb = 0.f;
        for (int w = 0; w < wave; ++w) wb = fmaf(sAw[w][n], wb, sBw[w][n]);
        h[n] = fmaf(ae, wb, be);
    }

    // Phase 3: re-run chunk with true initial state, 2-deep pipelined B+C
    float yv[8];
#pragma unroll
    for (int i = 0; i < 8; ++i) {
        const uint4 c0 = qb[i & 1][0], c1 = qb[i & 1][1];
        const uint4 c2 = qb[i & 1][2], c3 = qb[i & 1][3];
        if (i < 6) {
#pragma unroll
            for (int j = 0; j < 4; ++j)
                qb[i & 1][j] = BC[((i + 2) * 4 + j) * 256 + tid];
        }
        const __half* h0 = (const __half*)&c0;
        const __half* h1 = (const __half*)&c1;
        const __half* h2 = (const __half*)&c2;
        const __half* h3 = (const __half*)&c3;
        float Bl[N_], Cl[N_];
#pragma unroll
        for (int e = 0; e < 8; ++e) {
            Bl[e] = __half2float(h0[e]);
            Bl[8 + e] = __half2float(h1[e]);
            Cl[e] = __half2float(h2[e]);
            Cl[8 + e] = __half2float(h3[e]);
        }
        const float dl = del[i];
        const float dx = dl * x[i];
        float y = Dval * x[i];
#pragma unroll
        for (int n = 0; n < N_; ++n) {
            const float dA = __expf(dl * A[n]);
            h[n] = fmaf(dA, h[n], dx * Bl[n]);
            y = fmaf(h[n], Cl[n], y);
        }
        yv[i] = y;
    }
    float4* ov = (float4*)(out + (size_t)bkd * L_);
    ov[tid * 2]     = make_float4(yv[0], yv[1], yv[2], yv[3]);
    ov[tid * 2 + 1] = make_float4(yv[4], yv[5], yv[6], yv[7]);
}

extern "C" void kernel_launch(void* const* d_in, const int* in_sizes, int n_in,
                              void* d_out, int out_size, void* d_ws, size_t ws_size,
                              hipStream_t stream) {
    const float* xs = (const float*)d_in[0];       // (B,K,D,L)
    const float* A_logs = (const float*)d_in[1];   // (K*D, N)
    const float* Ds = (const float*)d_in[2];       // (K*D,)
    const float* dtw = (const float*)d_in[3];      // (K,D,R)
    const float* dtb = (const float*)d_in[4];      // (K,D)
    const float* xpw = (const float*)d_in[5];      // (K,C,D)
    float* out = (float*)d_out;                    // (B,K,D,L) fp32

    uint4* BCc = (uint4*)d_ws;                     // 16*8*4*256 uint4 = 2 MB
    float* dts_ws = (float*)(BCc + (size_t)B_ * K_ * 8 * 4 * 256);  // 768 KB

    proj_kernel<<<dim3(B_ * K_, 4, 6), 256, 0, stream>>>(xs, xpw, BCc, dts_ws);
    scan_kernel<<<B_ * K_ * D_, 256, 0, stream>>>(
        xs, A_logs, Ds, dtw, dtb, dts_ws, BCc, out);
}